// Round 11
// baseline (390.322 us; speedup 1.0000x reference)
//
#include <hip/hip_runtime.h>
#include <hip/hip_bf16.h>
#include <stdint.h>

// Round 11: ABLATION ROUND. Real kernels unchanged (round-9 version) produce
// the answer; four padded probe kernels (template MODE 0..3) decompose the
// runtime: pad-only / +stage / +MFMA-E-guard(no exp) / full. Padding (~51us
// dependent-FMA spin) lifts probes above the 43us ws-fill dispatches so they
// appear in the top-5 rocprof table. Phase cost = delta between probes.

#define P2 256
#define CF 32
#define ROWP 40   // bf16 row pitch: 80 B

using bf16x8 = __attribute__((ext_vector_type(8))) short;
using f32x4  = __attribute__((ext_vector_type(4))) float;

__device__ __forceinline__ short bfs(float x) {
    __hip_bfloat16 h = __float2bfloat16(x);
    union { __hip_bfloat16 h; short s; } u; u.h = h; return u.s;
}

// ---------------- real kernels (round-9, unchanged) ----------------

__global__ __launch_bounds__(256, 4)
void ncut_mfma_kernel(const float* __restrict__ pred,
                      const float* __restrict__ feat,
                      float* __restrict__ ws)
{
    __shared__ short  fb[P2][ROWP];
    __shared__ float2 sp[P2];
    __shared__ float  red[8];

    const int t  = threadIdx.x;
    const int l  = t & 63;
    const int w  = t >> 6;
    const int b  = blockIdx.x;
    const int n  = b >> 8, pl = b & 255;
    const int hp = pl >> 4, wp = pl & 15;

    const int pq  = t >> 2;
    const int y   = pq >> 2;
    const int k4  = pq & 3;
    const int cg0 = t & 3;

    const float* qbase = feat + (((size_t)n * CF) * 256 + hp * 16 + y) * 256
                              + wp * 16 + k4 * 4;
    float4 v[8];
#pragma unroll
    for (int it = 0; it < 2; ++it) {
        const int cg = cg0 + it * 4;
#pragma unroll
        for (int cc = 0; cc < 4; ++cc)
            v[it * 4 + cc] = *(const float4*)(qbase + (size_t)(cg * 4 + cc) * 65536);
    }
    const float p_mine = pred[(((size_t)n * 256) + hp * 16 + y) * 256
                              + wp * 16 + k4 * 4 + cg0];

    float psq0 = 0.f, psq1 = 0.f, psq2 = 0.f, psq3 = 0.f;
#pragma unroll
    for (int q8 = 0; q8 < 8; ++q8) {
        psq0 = fmaf(v[q8].x, v[q8].x, psq0);
        psq1 = fmaf(v[q8].y, v[q8].y, psq1);
        psq2 = fmaf(v[q8].z, v[q8].z, psq2);
        psq3 = fmaf(v[q8].w, v[q8].w, psq3);
    }
    psq0 += __shfl_xor(psq0, 1); psq0 += __shfl_xor(psq0, 2);
    psq1 += __shfl_xor(psq1, 1); psq1 += __shfl_xor(psq1, 2);
    psq2 += __shfl_xor(psq2, 1); psq2 += __shfl_xor(psq2, 2);
    psq3 += __shfl_xor(psq3, 1); psq3 += __shfl_xor(psq3, 2);
    float mysq = (cg0 == 0) ? psq0 : (cg0 == 1) ? psq1 : (cg0 == 2) ? psq2 : psq3;
    sp[pq * 4 + cg0] = make_float2(mysq, p_mine);

#pragma unroll
    for (int it = 0; it < 2; ++it) {
        const int cg = cg0 + it * 4;
        short4 o0 = { bfs(v[it*4+0].x), bfs(v[it*4+1].x), bfs(v[it*4+2].x), bfs(v[it*4+3].x) };
        short4 o1 = { bfs(v[it*4+0].y), bfs(v[it*4+1].y), bfs(v[it*4+2].y), bfs(v[it*4+3].y) };
        short4 o2 = { bfs(v[it*4+0].z), bfs(v[it*4+1].z), bfs(v[it*4+2].z), bfs(v[it*4+3].z) };
        short4 o3 = { bfs(v[it*4+0].w), bfs(v[it*4+1].w), bfs(v[it*4+2].w), bfs(v[it*4+3].w) };
        *(short4*)&fb[pq * 4 + 0][cg * 4] = o0;
        *(short4*)&fb[pq * 4 + 1][cg * 4] = o1;
        *(short4*)&fb[pq * 4 + 2][cg * 4] = o2;
        *(short4*)&fb[pq * 4 + 3][cg * 4] = o3;
    }
    __syncthreads();

    const int lr = l & 15;
    const int lk = l >> 4;

    bf16x8 af[4];
#pragma unroll
    for (int r = 0; r < 4; ++r)
        af[r] = *(const bf16x8*)&fb[(w * 4 + r) * 16 + lr][lk * 8];

    const float L50  = 72.134752f;
    const float L100 = 144.269504f;
    const float CSPL = -4.3333804e-8f;

    float a[4][4];
    float api[4][4];
#pragma unroll
    for (int tii = 0; tii < 4; ++tii)
#pragma unroll
        for (int r = 0; r < 4; ++r) {
            const int qi = lk * 4 + r;
            const float dq = (float)(qi - lr);
            a[tii][r] = fmaf(dq * dq, CSPL, -L50 * sp[(w * 4 + tii) * 16 + qi].x);
            api[tii][r] = 0.f;
        }

    const f32x4 zero = {0.f, 0.f, 0.f, 0.f};
    const float tif = (float)(w * 4);

#pragma unroll 2
    for (int tj = 0; tj < 16; ++tj) {
        const bf16x8 bfj = *(const bf16x8*)&fb[tj * 16 + lr][lk * 8];
        const float2 spc = sp[tj * 16 + lr];
        const float bbase = -L50 * spc.x;
        const float tjf = (float)tj;

        f32x4 acc[4];
#pragma unroll
        for (int tii = 0; tii < 4; ++tii)
            acc[tii] = __builtin_amdgcn_mfma_f32_16x16x32_bf16(af[tii], bfj, zero, 0, 0, 0);

        float E[4][4];
        float mx = -1e30f;
#pragma unroll
        for (int tii = 0; tii < 4; ++tii) {
            const float dyf = tif + (float)tii - tjf;
            const float bj = fmaf(dyf * dyf, CSPL, bbase);
#pragma unroll
            for (int r = 0; r < 4; ++r) {
                E[tii][r] = fmaf(L100, acc[tii][r], a[tii][r] + bj);
                mx = fmaxf(mx, E[tii][r]);
            }
        }

        if (__any(mx > -126.f)) {
#pragma unroll
            for (int tii = 0; tii < 4; ++tii) {
                const bool tdiag = (w * 4 + tii) == tj;
#pragma unroll
                for (int r = 0; r < 4; ++r) {
                    float e2 = E[tii][r];
                    if (tdiag && (lk * 4 + r) == lr) e2 = 0.f;
                    api[tii][r] = fmaf(__builtin_amdgcn_exp2f(e2), spc.y, api[tii][r]);
                }
            }
        }
    }

    float assoc = 0.f, cut = 0.f;
#pragma unroll
    for (int tii = 0; tii < 4; ++tii)
#pragma unroll
        for (int r = 0; r < 4; ++r) {
            const float pi = sp[(w * 4 + tii) * 16 + lk * 4 + r].y;
            assoc += api[tii][r];
            cut   = fmaf(1.f - pi, api[tii][r], cut);
        }
#pragma unroll
    for (int off = 32; off; off >>= 1) {
        assoc += __shfl_down(assoc, off);
        cut   += __shfl_down(cut,  off);
    }
    if (l == 0) { red[2 * w] = assoc; red[2 * w + 1] = cut; }
    __syncthreads();
    if (t == 0) {
        float aa = red[0] + red[2] + red[4] + red[6];
        float cc = red[1] + red[3] + red[5] + red[7];
        ws[b] = cc / (aa + 1e-5f);
    }
}

__global__ __launch_bounds__(256)
void ncut_reduce_kernel(const float* __restrict__ ws, float* __restrict__ out)
{
    __shared__ float red[4];
    const int t = threadIdx.x;
    float s = ws[t] + ws[t + 256] + ws[t + 512] + ws[t + 768];
#pragma unroll
    for (int off = 32; off; off >>= 1)
        s += __shfl_down(s, off);
    if ((t & 63) == 0) red[t >> 6] = s;
    __syncthreads();
    if (t == 0)
        out[0] = (red[0] + red[1] + red[2] + red[3]) * (1.0f / 1024.0f);
}

// ---------------- ablation probes ----------------
// MODE 0: padding only.  MODE 1: + staging.  MODE 2: + frag/MFMA/E/guard-ballot
// (no exp, digest keeps everything live).  MODE 3: + exp + epilogue (full).

template<int MODE>
__global__ __launch_bounds__(256, 4)
void ncut_probe(const float* __restrict__ pred,
                const float* __restrict__ feat,
                float* __restrict__ ws)
{
    __shared__ short  fb[P2][ROWP];
    __shared__ float2 sp[P2];

    const int t  = threadIdx.x;
    const int l  = t & 63;
    const int w  = t >> 6;
    const int b  = blockIdx.x;
    const int n  = b >> 8, pl = b & 255;
    const int hp = pl >> 4, wp = pl & 15;

    // ---- fixed padding: ~51 us dependent-FMA spin (identical in all MODEs) ----
    float x = fmaf(pred[t], 1e-30f, 1.0f);
    for (int k = 0; k < 1900; ++k) {
#pragma unroll
        for (int u = 0; u < 8; ++u)
            x = fmaf(x, 0.99990f, 1e-6f);
    }
    asm volatile("" : "+v"(x));
    float digest = x * 1e-20f;

    if constexpr (MODE >= 1) {
        const int pq  = t >> 2;
        const int y   = pq >> 2;
        const int k4  = pq & 3;
        const int cg0 = t & 3;
        const float* qbase = feat + (((size_t)n * CF) * 256 + hp * 16 + y) * 256
                                  + wp * 16 + k4 * 4;
        float4 v[8];
#pragma unroll
        for (int it = 0; it < 2; ++it) {
            const int cg = cg0 + it * 4;
#pragma unroll
            for (int cc = 0; cc < 4; ++cc)
                v[it * 4 + cc] = *(const float4*)(qbase + (size_t)(cg * 4 + cc) * 65536);
        }
        const float p_mine = pred[(((size_t)n * 256) + hp * 16 + y) * 256
                                  + wp * 16 + k4 * 4 + cg0];
        float psq0 = 0.f, psq1 = 0.f, psq2 = 0.f, psq3 = 0.f;
#pragma unroll
        for (int q8 = 0; q8 < 8; ++q8) {
            psq0 = fmaf(v[q8].x, v[q8].x, psq0);
            psq1 = fmaf(v[q8].y, v[q8].y, psq1);
            psq2 = fmaf(v[q8].z, v[q8].z, psq2);
            psq3 = fmaf(v[q8].w, v[q8].w, psq3);
        }
        psq0 += __shfl_xor(psq0, 1); psq0 += __shfl_xor(psq0, 2);
        psq1 += __shfl_xor(psq1, 1); psq1 += __shfl_xor(psq1, 2);
        psq2 += __shfl_xor(psq2, 1); psq2 += __shfl_xor(psq2, 2);
        psq3 += __shfl_xor(psq3, 1); psq3 += __shfl_xor(psq3, 2);
        float mysq = (cg0 == 0) ? psq0 : (cg0 == 1) ? psq1 : (cg0 == 2) ? psq2 : psq3;
        sp[pq * 4 + cg0] = make_float2(mysq, p_mine);

#pragma unroll
        for (int it = 0; it < 2; ++it) {
            const int cg = cg0 + it * 4;
            short4 o0 = { bfs(v[it*4+0].x), bfs(v[it*4+1].x), bfs(v[it*4+2].x), bfs(v[it*4+3].x) };
            short4 o1 = { bfs(v[it*4+0].y), bfs(v[it*4+1].y), bfs(v[it*4+2].y), bfs(v[it*4+3].y) };
            short4 o2 = { bfs(v[it*4+0].z), bfs(v[it*4+1].z), bfs(v[it*4+2].z), bfs(v[it*4+3].z) };
            short4 o3 = { bfs(v[it*4+0].w), bfs(v[it*4+1].w), bfs(v[it*4+2].w), bfs(v[it*4+3].w) };
            *(short4*)&fb[pq * 4 + 0][cg * 4] = o0;
            *(short4*)&fb[pq * 4 + 1][cg * 4] = o1;
            *(short4*)&fb[pq * 4 + 2][cg * 4] = o2;
            *(short4*)&fb[pq * 4 + 3][cg * 4] = o3;
        }
        __syncthreads();
        // keep LDS contents live (cross-thread read after barrier)
        digest += (float)fb[(t + 1) & 255][(t & 3) * 8] + sp[(t + 13) & 255].x;
    }

    if constexpr (MODE >= 2) {
        const int lr = l & 15;
        const int lk = l >> 4;
        bf16x8 af[4];
#pragma unroll
        for (int r = 0; r < 4; ++r)
            af[r] = *(const bf16x8*)&fb[(w * 4 + r) * 16 + lr][lk * 8];

        const float L50  = 72.134752f;
        const float L100 = 144.269504f;
        const float CSPL = -4.3333804e-8f;

        float a[4][4];
        float api[4][4];
#pragma unroll
        for (int tii = 0; tii < 4; ++tii)
#pragma unroll
            for (int r = 0; r < 4; ++r) {
                const int qi = lk * 4 + r;
                const float dq = (float)(qi - lr);
                a[tii][r] = fmaf(dq * dq, CSPL, -L50 * sp[(w * 4 + tii) * 16 + qi].x);
                api[tii][r] = 0.f;
            }

        const f32x4 zero = {0.f, 0.f, 0.f, 0.f};
        const float tif = (float)(w * 4);

#pragma unroll 2
        for (int tj = 0; tj < 16; ++tj) {
            const bf16x8 bfj = *(const bf16x8*)&fb[tj * 16 + lr][lk * 8];
            const float2 spc = sp[tj * 16 + lr];
            const float bbase = -L50 * spc.x;
            const float tjf = (float)tj;

            f32x4 acc[4];
#pragma unroll
            for (int tii = 0; tii < 4; ++tii)
                acc[tii] = __builtin_amdgcn_mfma_f32_16x16x32_bf16(af[tii], bfj, zero, 0, 0, 0);

            float E[4][4];
            float mx = -1e30f;
#pragma unroll
            for (int tii = 0; tii < 4; ++tii) {
                const float dyf = tif + (float)tii - tjf;
                const float bj = fmaf(dyf * dyf, CSPL, bbase);
#pragma unroll
                for (int r = 0; r < 4; ++r) {
                    E[tii][r] = fmaf(L100, acc[tii][r], a[tii][r] + bj);
                    mx = fmaxf(mx, E[tii][r]);
                }
            }

            if constexpr (MODE >= 3) {
                if (__any(mx > -126.f)) {
#pragma unroll
                    for (int tii = 0; tii < 4; ++tii) {
                        const bool tdiag = (w * 4 + tii) == tj;
#pragma unroll
                        for (int r = 0; r < 4; ++r) {
                            float e2 = E[tii][r];
                            if (tdiag && (lk * 4 + r) == lr) e2 = 0.f;
                            api[tii][r] = fmaf(__builtin_amdgcn_exp2f(e2), spc.y, api[tii][r]);
                        }
                    }
                }
            } else {
                // keep guard-ballot cost, keep E/mx live
                digest += (__any(mx > -126.f) ? 1.0f : 0.0f) + mx * 1e-6f;
            }
        }

        if constexpr (MODE >= 3) {
            float assoc = 0.f, cut = 0.f;
#pragma unroll
            for (int tii = 0; tii < 4; ++tii)
#pragma unroll
                for (int r = 0; r < 4; ++r) {
                    const float pi = sp[(w * 4 + tii) * 16 + lk * 4 + r].y;
                    assoc += api[tii][r];
                    cut   = fmaf(1.f - pi, api[tii][r], cut);
                }
#pragma unroll
            for (int off = 32; off; off >>= 1) {
                assoc += __shfl_down(assoc, off);
                cut   += __shfl_down(cut,  off);
            }
            digest += assoc + cut;
        }
    }

    // disjoint probe slots, far above the real ws[0..1023]
    ws[(size_t)(1 + MODE) * (1 << 18) + (size_t)b * 256 + t] = digest;
}

extern "C" void kernel_launch(void* const* d_in, const int* in_sizes, int n_in,
                              void* d_out, int out_size, void* d_ws, size_t ws_size,
                              hipStream_t stream)
{
    const float* pred = (const float*)d_in[0];   // (4,1,256,256) f32
    const float* feat = (const float*)d_in[1];   // (4,32,256,256) f32
    float* out = (float*)d_out;                  // scalar f32
    float* ws  = (float*)d_ws;

    // real computation (unchanged)
    ncut_mfma_kernel<<<1024, 256, 0, stream>>>(pred, feat, ws);
    ncut_reduce_kernel<<<1, 256, 0, stream>>>(ws, out);

    // ablation probes (padded; read via rocprof per-dispatch durations)
    ncut_probe<0><<<1024, 256, 0, stream>>>(pred, feat, ws);
    ncut_probe<1><<<1024, 256, 0, stream>>>(pred, feat, ws);
    ncut_probe<2><<<1024, 256, 0, stream>>>(pred, feat, ws);
    ncut_probe<3><<<1024, 256, 0, stream>>>(pred, feat, ws);
}

// Round 13
// 87.468 us; speedup vs baseline: 4.4625x; 4.4625x over previous
//
#include <hip/hip_runtime.h>
#include <hip/hip_bf16.h>
#include <stdint.h>

// Round 12: round-9 structure + (1) XCD-affinity block swizzle so each XCD
// stages a dense contiguous row-band slab (stage-wall HBM efficiency),
// (2) per-tii underflow guard (exp taken on 1/16 tiles instead of 4/16,
// drops the E[4][4] buffer). Compute core otherwise unchanged: bf16 MFMA
// Gram + log2-domain exponent + exact forced diagonal. No atomics.

#define P2 256
#define CF 32
#define ROWP 40   // bf16 row pitch: 80 B

using bf16x8 = __attribute__((ext_vector_type(8))) short;
using f32x4  = __attribute__((ext_vector_type(4))) float;

__device__ __forceinline__ short bfs(float x) {
    __hip_bfloat16 h = __float2bfloat16(x);
    union { __hip_bfloat16 h; short s; } u; u.h = h; return u.s;
}

__global__ __launch_bounds__(256, 4)
void ncut_mfma_kernel(const float* __restrict__ pred,
                      const float* __restrict__ feat,
                      float* __restrict__ ws)
{
    __shared__ short  fb[P2][ROWP];
    __shared__ float2 sp[P2];
    __shared__ float  red[8];

    const int t  = threadIdx.x;
    const int l  = t & 63;
    const int w  = t >> 6;
    // XCD-affinity swizzle: blocks dispatched round-robin over 8 XCDs;
    // give XCD x the contiguous logical patch range [128x, 128x+128) so each
    // XCD reads one dense ~8 MB slab of feat (1024 % 8 == 0 -> bijective).
    const int b  = blockIdx.x;
    const int pb = ((b & 7) << 7) | (b >> 3);
    const int n  = pb >> 8, pl = pb & 255;
    const int hp = pl >> 4, wp = pl & 15;

    const int pq  = t >> 2;        // pixel-quad 0..63
    const int y   = pq >> 2;       // patch row
    const int k4  = pq & 3;        // quad-in-row
    const int cg0 = t & 3;         // channel group

    // pred first (single dword, feeds the pre-barrier sp write)
    const float p_mine = pred[(((size_t)n * 256) + hp * 16 + y) * 256
                              + wp * 16 + k4 * 4 + cg0];

    const float* qbase = feat + (((size_t)n * CF) * 256 + hp * 16 + y) * 256
                              + wp * 16 + k4 * 4;
    float4 v[8];
#pragma unroll
    for (int it = 0; it < 2; ++it) {
        const int cg = cg0 + it * 4;
#pragma unroll
        for (int cc = 0; cc < 4; ++cc)
            v[it * 4 + cc] = *(const float4*)(qbase + (size_t)(cg * 4 + cc) * 65536);
    }

    float psq0 = 0.f, psq1 = 0.f, psq2 = 0.f, psq3 = 0.f;
#pragma unroll
    for (int q8 = 0; q8 < 8; ++q8) {
        psq0 = fmaf(v[q8].x, v[q8].x, psq0);
        psq1 = fmaf(v[q8].y, v[q8].y, psq1);
        psq2 = fmaf(v[q8].z, v[q8].z, psq2);
        psq3 = fmaf(v[q8].w, v[q8].w, psq3);
    }
    psq0 += __shfl_xor(psq0, 1); psq0 += __shfl_xor(psq0, 2);
    psq1 += __shfl_xor(psq1, 1); psq1 += __shfl_xor(psq1, 2);
    psq2 += __shfl_xor(psq2, 1); psq2 += __shfl_xor(psq2, 2);
    psq3 += __shfl_xor(psq3, 1); psq3 += __shfl_xor(psq3, 2);
    float mysq = (cg0 == 0) ? psq0 : (cg0 == 1) ? psq1 : (cg0 == 2) ? psq2 : psq3;
    sp[pq * 4 + cg0] = make_float2(mysq, p_mine);

#pragma unroll
    for (int it = 0; it < 2; ++it) {
        const int cg = cg0 + it * 4;
        short4 o0 = { bfs(v[it*4+0].x), bfs(v[it*4+1].x), bfs(v[it*4+2].x), bfs(v[it*4+3].x) };
        short4 o1 = { bfs(v[it*4+0].y), bfs(v[it*4+1].y), bfs(v[it*4+2].y), bfs(v[it*4+3].y) };
        short4 o2 = { bfs(v[it*4+0].z), bfs(v[it*4+1].z), bfs(v[it*4+2].z), bfs(v[it*4+3].z) };
        short4 o3 = { bfs(v[it*4+0].w), bfs(v[it*4+1].w), bfs(v[it*4+2].w), bfs(v[it*4+3].w) };
        *(short4*)&fb[pq * 4 + 0][cg * 4] = o0;
        *(short4*)&fb[pq * 4 + 1][cg * 4] = o1;
        *(short4*)&fb[pq * 4 + 2][cg * 4] = o2;
        *(short4*)&fb[pq * 4 + 3][cg * 4] = o3;
    }
    __syncthreads();

    const int lr = l & 15;
    const int lk = l >> 4;

    bf16x8 af[4];
#pragma unroll
    for (int r = 0; r < 4; ++r)
        af[r] = *(const bf16x8*)&fb[(w * 4 + r) * 16 + lr][lk * 8];

    const float L50  = 72.134752f;      // 50*log2(e)
    const float L100 = 144.269504f;     // 100*log2(e)
    const float CSPL = -4.3333804e-8f;  // -log2(e)/(2*256*65025)

    float a[4][4];
    float api[4][4];
#pragma unroll
    for (int tii = 0; tii < 4; ++tii)
#pragma unroll
        for (int r = 0; r < 4; ++r) {
            const int qi = lk * 4 + r;
            const float dq = (float)(qi - lr);
            a[tii][r] = fmaf(dq * dq, CSPL, -L50 * sp[(w * 4 + tii) * 16 + qi].x);
            api[tii][r] = 0.f;
        }

    const f32x4 zero = {0.f, 0.f, 0.f, 0.f};
    const float tif = (float)(w * 4);

#pragma unroll 2
    for (int tj = 0; tj < 16; ++tj) {
        const bf16x8 bfj = *(const bf16x8*)&fb[tj * 16 + lr][lk * 8];
        const float2 spc = sp[tj * 16 + lr];          // {sq_j, p_j}
        const float bbase = -L50 * spc.x;
        const float tjf = (float)tj;

        f32x4 acc[4];
#pragma unroll
        for (int tii = 0; tii < 4; ++tii)
            acc[tii] = __builtin_amdgcn_mfma_f32_16x16x32_bf16(af[tii], bfj, zero, 0, 0, 0);

#pragma unroll
        for (int tii = 0; tii < 4; ++tii) {
            const float dyf = tif + (float)tii - tjf;
            const float bj = fmaf(dyf * dyf, CSPL, bbase);
            const bool diag = (w * 4 + tii) == tj;

            float E0 = fmaf(L100, acc[tii][0], a[tii][0] + bj);
            float E1 = fmaf(L100, acc[tii][1], a[tii][1] + bj);
            float E2 = fmaf(L100, acc[tii][2], a[tii][2] + bj);
            float E3 = fmaf(L100, acc[tii][3], a[tii][3] + bj);
            const float mxi = fmaxf(fmaxf(E0, E1), fmaxf(E2, E3));

            // per-tile guard: exp2(x < -126) == 0.0f exactly; diagonal tile
            // always taken (its forced-zero entry survives).
            if (diag || __any(mxi > -126.f)) {
                if (diag) {
                    if ((lk * 4 + 0) == lr) E0 = 0.f;
                    if ((lk * 4 + 1) == lr) E1 = 0.f;
                    if ((lk * 4 + 2) == lr) E2 = 0.f;
                    if ((lk * 4 + 3) == lr) E3 = 0.f;
                }
                api[tii][0] = fmaf(__builtin_amdgcn_exp2f(E0), spc.y, api[tii][0]);
                api[tii][1] = fmaf(__builtin_amdgcn_exp2f(E1), spc.y, api[tii][1]);
                api[tii][2] = fmaf(__builtin_amdgcn_exp2f(E2), spc.y, api[tii][2]);
                api[tii][3] = fmaf(__builtin_amdgcn_exp2f(E3), spc.y, api[tii][3]);
            }
        }
    }

    float assoc = 0.f, cut = 0.f;
#pragma unroll
    for (int tii = 0; tii < 4; ++tii)
#pragma unroll
        for (int r = 0; r < 4; ++r) {
            const float pi = sp[(w * 4 + tii) * 16 + lk * 4 + r].y;
            assoc += api[tii][r];
            cut   = fmaf(1.f - pi, api[tii][r], cut);
        }
#pragma unroll
    for (int off = 32; off; off >>= 1) {
        assoc += __shfl_down(assoc, off);
        cut   += __shfl_down(cut,  off);
    }
    if (l == 0) { red[2 * w] = assoc; red[2 * w + 1] = cut; }
    __syncthreads();
    if (t == 0) {
        float aa = red[0] + red[2] + red[4] + red[6];
        float cc = red[1] + red[3] + red[5] + red[7];
        ws[pb] = cc / (aa + 1e-5f);
    }
}

__global__ __launch_bounds__(256)
void ncut_reduce_kernel(const float* __restrict__ ws, float* __restrict__ out)
{
    __shared__ float red[4];
    const int t = threadIdx.x;
    float s = ws[t] + ws[t + 256] + ws[t + 512] + ws[t + 768];
#pragma unroll
    for (int off = 32; off; off >>= 1)
        s += __shfl_down(s, off);
    if ((t & 63) == 0) red[t >> 6] = s;
    __syncthreads();
    if (t == 0)
        out[0] = (red[0] + red[1] + red[2] + red[3]) * (1.0f / 1024.0f);
}

extern "C" void kernel_launch(void* const* d_in, const int* in_sizes, int n_in,
                              void* d_out, int out_size, void* d_ws, size_t ws_size,
                              hipStream_t stream)
{
    const float* pred = (const float*)d_in[0];   // (4,1,256,256) f32
    const float* feat = (const float*)d_in[1];   // (4,32,256,256) f32
    float* out = (float*)d_out;                  // scalar f32
    float* ws  = (float*)d_ws;                   // per-patch losses (1024 f32)

    ncut_mfma_kernel<<<1024, 256, 0, stream>>>(pred, feat, ws);
    ncut_reduce_kernel<<<1, 256, 0, stream>>>(ws, out);
}